// Round 8
// baseline (2341.481 us; speedup 1.0000x reference)
//
#include <hip/hip_runtime.h>

#define NTOK  32768
#define NE    8192
#define DIM   256
#define EPSF  8.0e-4f   // candidate-collection slack (>= DSEL, proven sufficient r6/r7)
#define DSEL  4.5e-4f   // rigorous ambiguity bound: 2*bf16 score err + ref rounding
#define LCAP  14

typedef __attribute__((ext_vector_type(8))) short short8;
typedef __attribute__((ext_vector_type(4))) float f32x4;

static __device__ __forceinline__ unsigned pk32(float f) {
  unsigned u = __float_as_uint(f);
  return (u & 0x80000000u) ? ~u : (u | 0x80000000u);
}
static __device__ __forceinline__ float upk32(unsigned p) {
  unsigned u = (p & 0x80000000u) ? (p & 0x7fffffffu) : ~p;
  return __uint_as_float(u);
}
static __device__ __forceinline__ unsigned long long pk64(float s, int idx) {
  return ((unsigned long long)pk32(s) << 32) | (unsigned)idx;
}
static __device__ __forceinline__ unsigned short bf16rne(float f) {
  unsigned u = __float_as_uint(f);
  unsigned r = u + 0x7fffu + ((u >> 16) & 1u);
  return (unsigned short)(r >> 16);
}
static __device__ __forceinline__ void gld16(const void* g, void* l) {
  __builtin_amdgcn_global_load_lds(
      (const __attribute__((address_space(1))) unsigned int*)g,
      (__attribute__((address_space(3))) unsigned int*)l, 16, 0, 0);
}

// ---------------- K1: prep (z2/e2 numpy-pairwise exact, bf16 copies, inits) --
__global__ __launch_bounds__(256) void vq_prep(const float* __restrict__ z,
                                               const float* __restrict__ emb,
                                               float* __restrict__ e2,
                                               float* __restrict__ z2,
                                               unsigned* __restrict__ gmin,
                                               unsigned* __restrict__ cnt,
                                               unsigned* __restrict__ wcount,
                                               unsigned short* __restrict__ zb,
                                               unsigned short* __restrict__ eb,
                                               float* __restrict__ loss_slot) {
  int gid = blockIdx.x * 256 + threadIdx.x;
  if (gid < NTOK) { gmin[gid] = 0xFFFFFFFFu; cnt[gid] = 0u; }
  if (gid == 0) { loss_slot[0] = 0.0f; wcount[0] = 0u; }

  int wave = gid >> 6;
  int lane = threadIdx.x & 63;
  int row = wave * 16 + (lane >> 2);            // 0..40959
  int sub = lane & 3;
  int q = sub & 1, h = sub >> 1;

  const float* src = (row < NTOK) ? (z + (size_t)row * DIM)
                                  : (emb + (size_t)(row - NTOK) * DIM);
  unsigned short* dst = (row < NTOK) ? (zb + (size_t)row * DIM)
                                     : (eb + (size_t)(row - NTOK) * DIM);
  const float4* p = reinterpret_cast<const float4*>(src + h * 128 + q * 4);

  float r0, r1, r2, r3, s;
  {
    #pragma clang fp contract(off)
    r0 = 0.0f; r1 = 0.0f; r2 = 0.0f; r3 = 0.0f;
    #pragma unroll
    for (int t = 0; t < 16; t++) {
      float4 v = p[2 * t];
      ushort4 w;
      w.x = bf16rne(v.x); w.y = bf16rne(v.y); w.z = bf16rne(v.z); w.w = bf16rne(v.w);
      *reinterpret_cast<ushort4*>(dst + h * 128 + q * 4 + t * 8) = w;
      float q0 = v.x * v.x, q1 = v.y * v.y, q2 = v.z * v.z, q3 = v.w * v.w;
      r0 = r0 + q0; r1 = r1 + q1; r2 = r2 + q2; r3 = r3 + q3;
    }
    s = (r0 + r1) + (r2 + r3);
    s = s + __shfl_xor(s, 1, 64);
    s = s + __shfl_xor(s, 2, 64);
  }
  if (sub == 0) {
    if (row < NTOK) z2[row] = s;
    else            e2[row - NTOK] = s;
  }
}

// ---------------- K2: bf16 MFMA scoring. collect=0: per-token global min.
//                  collect=1: identical GEMM, emit (score,idx) <= gmin+eps ----
__global__ __launch_bounds__(256, 2) void vq_mfma(const unsigned short* __restrict__ zb,
                                                  const unsigned short* __restrict__ eb,
                                                  const float* __restrict__ e2,
                                                  unsigned* __restrict__ gmin,
                                                  unsigned* __restrict__ cnt,
                                                  unsigned long long* __restrict__ ent,
                                                  int collect) {
  __shared__ unsigned short Ab[128 * 32];
  __shared__ unsigned short Bb[128 * 32];
  __shared__ unsigned lmin[128];
  __shared__ float thrS[128];

  const int tid = threadIdx.x;
  const int t0 = blockIdx.x * 128;
  const int e0 = blockIdx.y * 128;
  if (tid < 128) lmin[tid] = 0xFFFFFFFFu;
  const int lane = tid & 63;
  const int wv = tid >> 6;
  const int wm = wv & 1, wn = wv >> 1;

  f32x4 acc[4][4];
  #pragma unroll
  for (int i = 0; i < 4; i++)
    #pragma unroll
    for (int j = 0; j < 4; j++) acc[i][j] = (f32x4)0.0f;

  const size_t gra = (size_t)(t0 + (tid >> 2)) * DIM + (tid & 3) * 8;
  const size_t grb = (size_t)(e0 + (tid >> 2)) * DIM + (tid & 3) * 8;
  char* la0 = (char*)Ab + tid * 16;
  char* lb0 = (char*)Bb + tid * 16;

  const int arix = (wm * 64 + (lane & 15)) * 32 + (lane >> 4) * 8;
  const int brix = (wn * 64 + (lane & 15)) * 32 + (lane >> 4) * 8;

  for (int kc = 0; kc < DIM; kc += 32) {
    __syncthreads();
    gld16(zb + gra + kc, la0);
    gld16(zb + gra + (size_t)64 * DIM + kc, la0 + 4096);
    gld16(eb + grb + kc, lb0);
    gld16(eb + grb + (size_t)64 * DIM + kc, lb0 + 4096);
    __syncthreads();
    short8 a[4], b[4];
    #pragma unroll
    for (int f = 0; f < 4; f++) {
      a[f] = *reinterpret_cast<const short8*>(&Ab[arix + f * 16 * 32]);
      b[f] = *reinterpret_cast<const short8*>(&Bb[brix + f * 16 * 32]);
    }
    #pragma unroll
    for (int fi = 0; fi < 4; fi++)
      #pragma unroll
      for (int fj = 0; fj < 4; fj++)
        acc[fi][fj] = __builtin_amdgcn_mfma_f32_16x16x32_bf16(a[fi], b[fj], acc[fi][fj], 0, 0, 0);
  }

  float e2c[4];
  #pragma unroll
  for (int fj = 0; fj < 4; fj++)
    e2c[fj] = e2[e0 + wn * 64 + fj * 16 + (lane & 15)];

  if (!collect) {
    #pragma unroll
    for (int fi = 0; fi < 4; fi++) {
      #pragma unroll
      for (int r = 0; r < 4; r++) {
        int tl = wm * 64 + fi * 16 + ((lane >> 4) << 2) + r;
        float mn = 1.0e30f;
        #pragma unroll
        for (int fj = 0; fj < 4; fj++) {
          float s = fmaf(-2.0f, acc[fi][fj][r], e2c[fj]);
          mn = fminf(mn, s);
        }
        atomicMin(&lmin[tl], pk32(mn));
      }
    }
    __syncthreads();
    if (tid < 128) atomicMin(&gmin[t0 + tid], lmin[tid]);
  } else {
    __syncthreads();
    if (tid < 128) thrS[tid] = upk32(gmin[t0 + tid]) + EPSF;
    __syncthreads();
    #pragma unroll
    for (int fi = 0; fi < 4; fi++) {
      #pragma unroll
      for (int r = 0; r < 4; r++) {
        int tl = wm * 64 + fi * 16 + ((lane >> 4) << 2) + r;
        float th = thrS[tl];
        #pragma unroll
        for (int fj = 0; fj < 4; fj++) {
          float s = fmaf(-2.0f, acc[fi][fj][r], e2c[fj]);
          if (s <= th) {
            int t = t0 + tl;
            unsigned pos = atomicAdd(&cnt[t], 1u);
            if (pos < LCAP)
              ent[(size_t)t * LCAP + pos] = pk64(s, e0 + wn * 64 + fj * 16 + (lane & 15));
          }
        }
      }
    }
  }
}

// ---------------- K3a: decide tokens; ambiguous ones go to worklist ----------
__global__ __launch_bounds__(256) void vq_pick(const unsigned* __restrict__ cnt,
                                               const unsigned long long* __restrict__ ent,
                                               unsigned* __restrict__ winners,
                                               unsigned* __restrict__ work,
                                               unsigned* __restrict__ wcount) {
  int t = blockIdx.x * 256 + threadIdx.x;
  unsigned c = cnt[t];
  bool ambig;
  unsigned win = 0;
  if (c <= LCAP) {
    unsigned long long best = ~0ull, second = ~0ull;
    for (unsigned j = 0; j < c; j++) {
      unsigned long long v = ent[(size_t)t * LCAP + j];
      if (v < best) { second = best; best = v; }
      else if (v < second) { second = v; }
    }
    win = (unsigned)(best & 0xffffffffu);
    if (c == 1) {
      ambig = false;
    } else {
      float s1 = upk32((unsigned)(best >> 32));
      float s2 = upk32((unsigned)(second >> 32));
      ambig = !(s2 > s1 + DSEL);   // gap > D => bf16 argmin == ref argmin
    }
  } else {
    ambig = true;                   // overflow: full exact scan
  }
  if (!ambig) winners[t] = win;
  else        work[atomicAdd(wcount, 1u)] = (unsigned)t;
}

// ---------------- K3b: exact fp32 chains for ambiguous tokens ----------------
__global__ __launch_bounds__(64) void vq_chain(const float* __restrict__ z,
                                               const float* __restrict__ emb,
                                               const float* __restrict__ z2,
                                               const float* __restrict__ e2,
                                               const unsigned* __restrict__ cnt,
                                               const unsigned long long* __restrict__ ent,
                                               const unsigned* __restrict__ work,
                                               const unsigned* __restrict__ wcount,
                                               unsigned* __restrict__ winners) {
  __shared__ float zr[256];
  __shared__ float esh[LCAP][260];
  const int lane = threadIdx.x;
  const int nw = (int)wcount[0];

  for (int i = blockIdx.x; i < nw; i += gridDim.x) {
    int t = (int)work[i];
    unsigned c = cnt[t];
    // stage z row (coalesced)
    float4 zv = reinterpret_cast<const float4*>(z + (size_t)t * DIM)[lane];
    *reinterpret_cast<float4*>(&zr[lane * 4]) = zv;
    const float z2t = z2[t];
    unsigned long long best = ~0ull;

    if (c <= LCAP) {
      unsigned long long e = (lane < (int)c) ? ent[(size_t)t * LCAP + lane] : ~0ull;
      unsigned long long m = e;
      #pragma unroll
      for (int off = 32; off > 0; off >>= 1) {
        unsigned long long o = __shfl_xor(m, off, 64);
        m = o < m ? o : m;
      }
      float smin = upk32((unsigned)(m >> 32));
      bool sel = (lane < (int)c) && (upk32((unsigned)(e >> 32)) <= smin + DSEL);
      unsigned long long selmask = __ballot(sel);
      int myslot = __popcll(selmask & ((lane == 63) ? ~0ull >> 1 : ((1ull << lane) - 1ull)));
      // stage selected candidate rows (coalesced, one row per pass)
      unsigned long long mm = selmask;
      for (int s2 = 0; mm; s2++) {
        int b = (int)__builtin_ctzll(mm);
        mm &= mm - 1;
        int cidx = (int)(__shfl(e, b) & 0xffffffffull);
        float4 ev = reinterpret_cast<const float4*>(emb + (size_t)cidx * DIM)[lane];
        *reinterpret_cast<float4*>(&esh[s2][lane * 4]) = ev;
      }
      __syncthreads();
      if (sel) {
        int cidx = (int)(e & 0xffffffffull);
        const float* er = &esh[myslot][0];
        float mv;
        {
          #pragma clang fp contract(off)
          mv = 0.0f;
          #pragma unroll 8
          for (int k = 0; k < DIM; k++) mv = fmaf(2.0f * zr[k], er[k], mv);
          float s = (z2t - mv) + e2[cidx];
          best = pk64(s, cidx);
        }
      }
    } else {
      // overflow (statistically never): exact full scan
      __syncthreads();
      for (int cb = 0; cb < NE / 64; cb++) {
        int cidx = cb * 64 + lane;
        const float* er = emb + (size_t)cidx * DIM;
        float mv;
        {
          #pragma clang fp contract(off)
          mv = 0.0f;
          #pragma unroll 8
          for (int k = 0; k < DIM; k++) mv = fmaf(2.0f * zr[k], er[k], mv);
          float s = (z2t - mv) + e2[cidx];
          unsigned long long kk = pk64(s, cidx);
          best = kk < best ? kk : best;
        }
      }
    }
    #pragma unroll
    for (int off = 32; off > 0; off >>= 1) {
      unsigned long long o = __shfl_xor(best, off, 64);
      best = o < best ? o : best;
    }
    if (lane == 0) winners[t] = (unsigned)(best & 0xffffffffu);
    __syncthreads();   // protect LDS before next item
  }
}

// ---------------- K4: gather zq = emb[winner], idx, loss (fb_out structure) --
__global__ __launch_bounds__(256) void vq_emit(const float* __restrict__ z,
                                               const float* __restrict__ emb,
                                               const unsigned* __restrict__ winners,
                                               float* __restrict__ out_zq,
                                               float* __restrict__ out_loss,
                                               float* __restrict__ out_idx) {
  __shared__ float lsum[4];
  const int wid = threadIdx.x >> 6;
  const int lane = threadIdx.x & 63;
  const int tbase = blockIdx.x * 16 + wid * 4;
  float s_acc = 0.0f;
  #pragma unroll
  for (int it = 0; it < 4; it++) {
    int t = tbase + it;
    unsigned idx = winners[t];
    float4 e = reinterpret_cast<const float4*>(emb + (size_t)idx * DIM)[lane];
    float4 zz = reinterpret_cast<const float4*>(z + (size_t)t * DIM)[lane];
    reinterpret_cast<float4*>(out_zq + (size_t)t * DIM)[lane] = e;
    float dx = e.x - zz.x, dy = e.y - zz.y, dz = e.z - zz.z, dw = e.w - zz.w;
    s_acc += dx * dx + dy * dy + dz * dz + dw * dw;
    if (lane == 0) out_idx[t] = (float)idx;
  }
  #pragma unroll
  for (int off = 32; off > 0; off >>= 1) s_acc += __shfl_down(s_acc, off, 64);
  if (lane == 0) lsum[wid] = s_acc;
  __syncthreads();
  if (threadIdx.x == 0) {
    float tot = (lsum[0] + lsum[1] + lsum[2] + lsum[3]) * (1.25f / 8388608.0f);
    atomicAdd(out_loss, tot);
  }
}

// ====================== round-3 verified fallback path =======================
#define BT 128
#define BE 128
#define BK 32
#define LDW 132

__global__ __launch_bounds__(256) void fb_init(const float* __restrict__ z,
                                               const float* __restrict__ emb,
                                               float* __restrict__ e2,
                                               float* __restrict__ z2,
                                               unsigned long long* __restrict__ k1,
                                               float* __restrict__ loss_slot) {
  int gid = blockIdx.x * 256 + threadIdx.x;
  if (gid < NTOK) k1[gid] = ~0ull;
  if (gid == 0) loss_slot[0] = 0.0f;
  int wave = gid >> 6;
  int lane = threadIdx.x & 63;
  int row = wave * 16 + (lane >> 2);
  int sub = lane & 3;
  int q = sub & 1, h = sub >> 1;
  const float* src = (row < NTOK) ? (z + (size_t)row * DIM)
                                  : (emb + (size_t)(row - NTOK) * DIM);
  const float4* p = reinterpret_cast<const float4*>(src + h * 128 + q * 4);
  float r0, r1, r2, r3, s;
  {
    #pragma clang fp contract(off)
    r0 = 0.0f; r1 = 0.0f; r2 = 0.0f; r3 = 0.0f;
    #pragma unroll
    for (int t = 0; t < 16; t++) {
      float4 v = p[2 * t];
      float q0 = v.x * v.x, q1 = v.y * v.y, q2 = v.z * v.z, q3 = v.w * v.w;
      r0 = r0 + q0; r1 = r1 + q1; r2 = r2 + q2; r3 = r3 + q3;
    }
    s = (r0 + r1) + (r2 + r3);
    s = s + __shfl_xor(s, 1, 64);
    s = s + __shfl_xor(s, 2, 64);
  }
  if (sub == 0) {
    if (row < NTOK) z2[row] = s;
    else            e2[row - NTOK] = s;
  }
}

__global__ __launch_bounds__(256, 4) void fb_score(const float* __restrict__ z,
                                                   const float* __restrict__ emb,
                                                   const float* __restrict__ e2,
                                                   const float* __restrict__ z2,
                                                   unsigned long long* __restrict__ k1) {
  __shared__ float As[BK][LDW];
  __shared__ float Bs[BK][LDW];
  __shared__ unsigned long long mkey[BT];
  const int tid = threadIdx.x;
  const int t0 = blockIdx.x * BT;
  const int e0 = blockIdx.y * BE;
  const int tx = tid & 15;
  const int ty = tid >> 4;
  if (tid < BT) mkey[tid] = ~0ull;
  float acc[8][8];
  #pragma unroll
  for (int i = 0; i < 8; i++)
    #pragma unroll
    for (int j = 0; j < 8; j++) acc[i][j] = 0.0f;
  const float* __restrict__ zt = z + (size_t)t0 * DIM;
  const float* __restrict__ et = emb + (size_t)e0 * DIM;
  for (int kc = 0; kc < DIM; kc += BK) {
    __syncthreads();
    #pragma unroll
    for (int i = 0; i < 4; i++) {
      int f = tid + i * 256;
      int row = f >> 3;
      int kq = f & 7;
      const float4 va = *reinterpret_cast<const float4*>(zt + row * DIM + kc + kq * 4);
      const float4 vb = *reinterpret_cast<const float4*>(et + row * DIM + kc + kq * 4);
      int k = kq * 4;
      As[k + 0][row] = va.x * 2.0f; As[k + 1][row] = va.y * 2.0f;
      As[k + 2][row] = va.z * 2.0f; As[k + 3][row] = va.w * 2.0f;
      Bs[k + 0][row] = vb.x; Bs[k + 1][row] = vb.y;
      Bs[k + 2][row] = vb.z; Bs[k + 3][row] = vb.w;
    }
    __syncthreads();
    #pragma unroll 4
    for (int k = 0; k < BK; k++) {
      float a[8], b[8];
      *(float4*)&a[0] = *(const float4*)&As[k][ty * 8];
      *(float4*)&a[4] = *(const float4*)&As[k][ty * 8 + 4];
      *(float4*)&b[0] = *(const float4*)&Bs[k][tx * 8];
      *(float4*)&b[4] = *(const float4*)&Bs[k][tx * 8 + 4];
      #pragma unroll
      for (int i = 0; i < 8; i++)
        #pragma unroll
        for (int j = 0; j < 8; j++)
          acc[i][j] = fmaf(a[i], b[j], acc[i][j]);
    }
  }
  float e2c[8], z2t[8];
  *(float4*)&e2c[0] = *(const float4*)(e2 + e0 + tx * 8);
  *(float4*)&e2c[4] = *(const float4*)(e2 + e0 + tx * 8 + 4);
  *(float4*)&z2t[0] = *(const float4*)(z2 + t0 + ty * 8);
  *(float4*)&z2t[4] = *(const float4*)(z2 + t0 + ty * 8 + 4);
  {
    #pragma clang fp contract(off)
    #pragma unroll
    for (int i = 0; i < 8; i++) {
      int trow = ty * 8 + i;
      unsigned long long best = ~0ull;
      #pragma unroll
      for (int j = 0; j < 8; j++) {
        float t1 = z2t[i] - acc[i][j];
        float s = t1 + e2c[j];
        unsigned long long kk = pk64(s, e0 + tx * 8 + j);
        best = kk < best ? kk : best;
      }
      atomicMin(&mkey[trow], best);
    }
  }
  __syncthreads();
  if (tid < BT) atomicMin(&k1[t0 + tid], mkey[tid]);
}

__global__ __launch_bounds__(256) void fb_out(const float* __restrict__ z,
                                              const float* __restrict__ emb,
                                              const unsigned long long* __restrict__ k1,
                                              float* __restrict__ out_zq,
                                              float* __restrict__ out_loss,
                                              float* __restrict__ out_idx) {
  __shared__ float lsum[4];
  const int wid = threadIdx.x >> 6;
  const int lane = threadIdx.x & 63;
  const int tbase = blockIdx.x * 16 + wid * 4;
  float s_acc = 0.0f;
  #pragma unroll
  for (int it = 0; it < 4; it++) {
    int t = tbase + it;
    unsigned idx = (unsigned)(k1[t] & 0xffffffffu);
    float4 e = reinterpret_cast<const float4*>(emb + (size_t)idx * DIM)[lane];
    float4 zz = reinterpret_cast<const float4*>(z + (size_t)t * DIM)[lane];
    reinterpret_cast<float4*>(out_zq + (size_t)t * DIM)[lane] = e;
    float dx = e.x - zz.x, dy = e.y - zz.y, dz = e.z - zz.z, dw = e.w - zz.w;
    s_acc += dx * dx + dy * dy + dz * dz + dw * dw;
    if (lane == 0) out_idx[t] = (float)idx;
  }
  #pragma unroll
  for (int off = 32; off > 0; off >>= 1) s_acc += __shfl_down(s_acc, off, 64);
  if (lane == 0) lsum[wid] = s_acc;
  __syncthreads();
  if (threadIdx.x == 0) {
    float tot = (lsum[0] + lsum[1] + lsum[2] + lsum[3]) * (1.25f / 8388608.0f);
    atomicAdd(out_loss, tot);
  }
}

// ============================== launcher =====================================
extern "C" void kernel_launch(void* const* d_in, const int* in_sizes, int n_in,
                              void* d_out, int out_size, void* d_ws, size_t ws_size,
                              hipStream_t stream) {
  const float* z = (const float*)d_in[0];
  const float* emb = (const float*)d_in[1];
  float* out = (float*)d_out;
  float* out_zq = out;
  float* out_loss = out + (size_t)NTOK * DIM;
  float* out_idx = out_loss + 1;

  // ws: e2 | z2 | gmin/winners | cnt | wcount | ent | work | zb | eb
  const size_t OFF_Z2   = 32768;
  const size_t OFF_GMIN = 163840;
  const size_t OFF_CNT  = 294912;
  const size_t OFF_WC   = 425984;
  const size_t OFF_ENT  = 426240;
  const size_t OFF_WORK = 4096256;
  const size_t OFF_ZB   = 4227328;
  const size_t OFF_EB   = 21004544;
  const size_t REQ      = 25198848;

  if (ws_size >= REQ) {
    float* e2 = (float*)d_ws;
    float* z2 = (float*)((char*)d_ws + OFF_Z2);
    unsigned* gmin = (unsigned*)((char*)d_ws + OFF_GMIN);   // reused as winners
    unsigned* cnt = (unsigned*)((char*)d_ws + OFF_CNT);
    unsigned* wcount = (unsigned*)((char*)d_ws + OFF_WC);
    unsigned long long* ent = (unsigned long long*)((char*)d_ws + OFF_ENT);
    unsigned* work = (unsigned*)((char*)d_ws + OFF_WORK);
    unsigned short* zb = (unsigned short*)((char*)d_ws + OFF_ZB);
    unsigned short* eb = (unsigned short*)((char*)d_ws + OFF_EB);

    hipLaunchKernelGGL(vq_prep, dim3(640), dim3(256), 0, stream,
                       z, emb, e2, z2, gmin, cnt, wcount, zb, eb, out_loss);
    hipLaunchKernelGGL(vq_mfma, dim3(NTOK / 128, NE / 128), dim3(256), 0, stream,
                       zb, eb, e2, gmin, cnt, ent, 0);
    hipLaunchKernelGGL(vq_mfma, dim3(NTOK / 128, NE / 128), dim3(256), 0, stream,
                       zb, eb, e2, gmin, cnt, ent, 1);
    hipLaunchKernelGGL(vq_pick, dim3(NTOK / 256), dim3(256), 0, stream,
                       cnt, ent, gmin, work, wcount);
    hipLaunchKernelGGL(vq_chain, dim3(2048), dim3(64), 0, stream,
                       z, emb, z2, e2, cnt, ent, work, wcount, gmin);
    hipLaunchKernelGGL(vq_emit, dim3(NTOK / 16), dim3(256), 0, stream,
                       z, emb, gmin, out_zq, out_loss, out_idx);
  } else {
    float* e2 = (float*)d_ws;
    float* z2 = (float*)((char*)d_ws + 32768);
    unsigned long long* k1 = (unsigned long long*)((char*)d_ws + 262144);
    hipLaunchKernelGGL(fb_init, dim3(640), dim3(256), 0, stream,
                       z, emb, e2, z2, k1, out_loss);
    hipLaunchKernelGGL(fb_score, dim3(NTOK / BT, NE / BE), dim3(256), 0, stream,
                       z, emb, e2, z2, k1);
    hipLaunchKernelGGL(fb_out, dim3(NTOK / 16), dim3(256), 0, stream,
                       z, emb, k1, out_zq, out_loss, out_idx);
  }
}

// Round 9
// 608.815 us; speedup vs baseline: 3.8460x; 3.8460x over previous
//
#include <hip/hip_runtime.h>

#define NTOK  32768
#define NE    8192
#define DIM   256
#define EPSF  5.0e-4f   // candidate-collection slack (>= 2*delta bound 3.2e-4)
#define DSELQ 4.8e-4f   // ambiguity bound on quantized keys (4.5e-4 + quantum slop)
#define LCAP  29

typedef __attribute__((ext_vector_type(8))) short short8;
typedef __attribute__((ext_vector_type(4))) float f32x4;

static __device__ __forceinline__ unsigned pk32(float f) {
  unsigned u = __float_as_uint(f);
  return (u & 0x80000000u) ? ~u : (u | 0x80000000u);
}
static __device__ __forceinline__ float upk32(unsigned p) {
  unsigned u = (p & 0x80000000u) ? (p & 0x7fffffffu) : ~p;
  return __uint_as_float(u);
}
static __device__ __forceinline__ unsigned long long pk64(float s, int idx) {
  return ((unsigned long long)pk32(s) << 32) | (unsigned)idx;
}
static __device__ __forceinline__ unsigned short bf16rne(float f) {
  unsigned u = __float_as_uint(f);
  unsigned r = u + 0x7fffu + ((u >> 16) & 1u);
  return (unsigned short)(r >> 16);
}
static __device__ __forceinline__ void gld16(const void* g, void* l) {
  __builtin_amdgcn_global_load_lds(
      (const __attribute__((address_space(1))) unsigned int*)g,
      (__attribute__((address_space(3))) unsigned int*)l, 16, 0, 0);
}

// ---------------- K1: prep (z2/e2 numpy-pairwise exact, bf16 copies, inits) --
__global__ __launch_bounds__(256) void vq_prep(const float* __restrict__ z,
                                               const float* __restrict__ emb,
                                               float* __restrict__ e2,
                                               float* __restrict__ z2,
                                               unsigned* __restrict__ gmin,
                                               unsigned* __restrict__ cnt,
                                               unsigned* __restrict__ work,
                                               unsigned short* __restrict__ zb,
                                               unsigned short* __restrict__ eb,
                                               float* __restrict__ loss_slot) {
  int gid = blockIdx.x * 256 + threadIdx.x;
  if (gid < NTOK) { gmin[gid] = 0xFFFFFFFFu; cnt[gid] = 0u; }
  if (gid == 0) { loss_slot[0] = 0.0f; work[0] = 0u; }

  int wave = gid >> 6;
  int lane = threadIdx.x & 63;
  int row = wave * 16 + (lane >> 2);            // 0..40959
  int sub = lane & 3;
  int q = sub & 1, h = sub >> 1;

  const float* src = (row < NTOK) ? (z + (size_t)row * DIM)
                                  : (emb + (size_t)(row - NTOK) * DIM);
  unsigned short* dst = (row < NTOK) ? (zb + (size_t)row * DIM)
                                     : (eb + (size_t)(row - NTOK) * DIM);
  const float4* p = reinterpret_cast<const float4*>(src + h * 128 + q * 4);

  float r0, r1, r2, r3, s;
  {
    #pragma clang fp contract(off)
    r0 = 0.0f; r1 = 0.0f; r2 = 0.0f; r3 = 0.0f;
    #pragma unroll
    for (int t = 0; t < 16; t++) {
      float4 v = p[2 * t];
      ushort4 w;
      w.x = bf16rne(v.x); w.y = bf16rne(v.y); w.z = bf16rne(v.z); w.w = bf16rne(v.w);
      *reinterpret_cast<ushort4*>(dst + h * 128 + q * 4 + t * 8) = w;
      float q0 = v.x * v.x, q1 = v.y * v.y, q2 = v.z * v.z, q3 = v.w * v.w;
      r0 = r0 + q0; r1 = r1 + q1; r2 = r2 + q2; r3 = r3 + q3;
    }
    s = (r0 + r1) + (r2 + r3);
    s = s + __shfl_xor(s, 1, 64);
    s = s + __shfl_xor(s, 2, 64);
  }
  if (sub == 0) {
    if (row < NTOK) z2[row] = s;
    else            e2[row - NTOK] = s;
  }
}

// ---------------- K2: bf16 MFMA scoring. collect=0: per-token global min.
//            collect=1: identical GEMM, emit u32 (key19|idx13) <= gmin+eps ----
__global__ __launch_bounds__(256, 2) void vq_mfma(const unsigned short* __restrict__ zb,
                                                  const unsigned short* __restrict__ eb,
                                                  const float* __restrict__ e2,
                                                  unsigned* __restrict__ gmin,
                                                  unsigned* __restrict__ cnt,
                                                  unsigned* __restrict__ ent,
                                                  int collect) {
  __shared__ unsigned short Ab[128 * 32];
  __shared__ unsigned short Bb[128 * 32];
  __shared__ unsigned lmin[128];
  __shared__ float thrS[128];

  const int tid = threadIdx.x;
  const int t0 = blockIdx.x * 128;
  const int e0 = blockIdx.y * 128;
  if (tid < 128) lmin[tid] = 0xFFFFFFFFu;
  const int lane = tid & 63;
  const int wv = tid >> 6;
  const int wm = wv & 1, wn = wv >> 1;

  f32x4 acc[4][4];
  #pragma unroll
  for (int i = 0; i < 4; i++)
    #pragma unroll
    for (int j = 0; j < 4; j++) acc[i][j] = (f32x4)0.0f;

  const size_t gra = (size_t)(t0 + (tid >> 2)) * DIM + (tid & 3) * 8;
  const size_t grb = (size_t)(e0 + (tid >> 2)) * DIM + (tid & 3) * 8;
  char* la0 = (char*)Ab + tid * 16;
  char* lb0 = (char*)Bb + tid * 16;

  const int arix = (wm * 64 + (lane & 15)) * 32 + (lane >> 4) * 8;
  const int brix = (wn * 64 + (lane & 15)) * 32 + (lane >> 4) * 8;

  for (int kc = 0; kc < DIM; kc += 32) {
    __syncthreads();
    gld16(zb + gra + kc, la0);
    gld16(zb + gra + (size_t)64 * DIM + kc, la0 + 4096);
    gld16(eb + grb + kc, lb0);
    gld16(eb + grb + (size_t)64 * DIM + kc, lb0 + 4096);
    __syncthreads();
    short8 a[4], b[4];
    #pragma unroll
    for (int f = 0; f < 4; f++) {
      a[f] = *reinterpret_cast<const short8*>(&Ab[arix + f * 16 * 32]);
      b[f] = *reinterpret_cast<const short8*>(&Bb[brix + f * 16 * 32]);
    }
    #pragma unroll
    for (int fi = 0; fi < 4; fi++)
      #pragma unroll
      for (int fj = 0; fj < 4; fj++)
        acc[fi][fj] = __builtin_amdgcn_mfma_f32_16x16x32_bf16(a[fi], b[fj], acc[fi][fj], 0, 0, 0);
  }

  float e2c[4];
  #pragma unroll
  for (int fj = 0; fj < 4; fj++)
    e2c[fj] = e2[e0 + wn * 64 + fj * 16 + (lane & 15)];

  if (!collect) {
    #pragma unroll
    for (int fi = 0; fi < 4; fi++) {
      #pragma unroll
      for (int r = 0; r < 4; r++) {
        int tl = wm * 64 + fi * 16 + ((lane >> 4) << 2) + r;
        float mn = 1.0e30f;
        #pragma unroll
        for (int fj = 0; fj < 4; fj++) {
          float s = fmaf(-2.0f, acc[fi][fj][r], e2c[fj]);
          mn = fminf(mn, s);
        }
        atomicMin(&lmin[tl], pk32(mn));
      }
    }
    __syncthreads();
    if (tid < 128) atomicMin(&gmin[t0 + tid], lmin[tid]);
  } else {
    __syncthreads();
    if (tid < 128) thrS[tid] = upk32(gmin[t0 + tid]) + EPSF;
    __syncthreads();
    #pragma unroll
    for (int fi = 0; fi < 4; fi++) {
      #pragma unroll
      for (int r = 0; r < 4; r++) {
        int tl = wm * 64 + fi * 16 + ((lane >> 4) << 2) + r;
        float th = thrS[tl];
        #pragma unroll
        for (int fj = 0; fj < 4; fj++) {
          float s = fmaf(-2.0f, acc[fi][fj][r], e2c[fj]);
          if (s <= th) {
            int t = t0 + tl;
            unsigned pos = atomicAdd(&cnt[t], 1u);
            if (pos < LCAP)
              ent[(size_t)t * LCAP + pos] =
                  (pk32(s) & 0xFFFFE000u) | (unsigned)(e0 + wn * 64 + fj * 16 + (lane & 15));
          }
        }
      }
    }
  }
}

// ---------------- K3a: decide tokens; ambiguous ones go to worklist ----------
__global__ __launch_bounds__(256) void vq_pick(const unsigned* __restrict__ cnt,
                                               const unsigned* __restrict__ ent,
                                               unsigned* __restrict__ winners,
                                               unsigned* __restrict__ work) {
  int t = blockIdx.x * 256 + threadIdx.x;
  unsigned c = cnt[t];
  bool ambig;
  unsigned win = 0;
  if (c <= LCAP) {
    unsigned best = 0xFFFFFFFFu, second = 0xFFFFFFFFu;
    for (unsigned j = 0; j < c; j++) {
      unsigned v = ent[(size_t)t * LCAP + j];
      if (v < best) { second = best; best = v; }
      else if (v < second) { second = v; }
    }
    win = best & 0x1FFFu;
    if (c <= 1) {
      ambig = false;
    } else {
      float s1 = upk32(best & 0xFFFFE000u);
      float s2 = upk32(second & 0xFFFFE000u);
      ambig = !(s2 > s1 + DSELQ);   // quantized gap > DSELQ => true gap > 4.5e-4
    }
  } else {
    ambig = true;                   // overflow (P ~ 1e-20): exact full scan
  }
  if (!ambig) winners[t] = win;
  else        work[1 + atomicAdd(&work[0], 1u)] = (unsigned)t;
}

// ---------------- K3b: exact fp32 chains for ambiguous tokens ----------------
// One wave per item; candidate-per-lane; z row broadcast from LDS; emb rows
// per-lane gather (few lanes active, unroll-8 keeps 8 loads in flight).
__global__ __launch_bounds__(64) void vq_chain(const float* __restrict__ z,
                                               const float* __restrict__ emb,
                                               const float* __restrict__ z2,
                                               const float* __restrict__ e2,
                                               const unsigned* __restrict__ cnt,
                                               const unsigned* __restrict__ ent,
                                               const unsigned* __restrict__ work,
                                               unsigned* __restrict__ winners) {
  __shared__ float zr[256];
  const int lane = threadIdx.x;
  const int nw = (int)work[0];

  for (int i = blockIdx.x; i < nw; i += gridDim.x) {
    int t = (int)work[1 + i];
    float4 zv = reinterpret_cast<const float4*>(z + (size_t)t * DIM)[lane];
    *reinterpret_cast<float4*>(&zr[lane * 4]) = zv;
    __syncthreads();
    const float z2t = z2[t];
    unsigned c = cnt[t];
    unsigned long long best = ~0ull;

    if (c <= LCAP) {
      if (lane < (int)c) {
        int cidx = (int)(ent[(size_t)t * LCAP + lane] & 0x1FFFu);
        const float* er = emb + (size_t)cidx * DIM;
        float m;
        {
          #pragma clang fp contract(off)
          m = 0.0f;
          #pragma unroll 8
          for (int k = 0; k < DIM; k++) m = fmaf(2.0f * zr[k], er[k], m);
          float s = (z2t - m) + e2[cidx];
          best = pk64(s, cidx);
        }
      }
    } else {
      // overflow fallback (statistically never): exact full scan
      for (int cb = 0; cb < NE / 64; cb++) {
        int cidx = cb * 64 + lane;
        const float* er = emb + (size_t)cidx * DIM;
        float m;
        {
          #pragma clang fp contract(off)
          m = 0.0f;
          #pragma unroll 8
          for (int k = 0; k < DIM; k++) m = fmaf(2.0f * zr[k], er[k], m);
          float s = (z2t - m) + e2[cidx];
          unsigned long long kk = pk64(s, cidx);
          best = kk < best ? kk : best;
        }
      }
    }
    #pragma unroll
    for (int off = 32; off > 0; off >>= 1) {
      unsigned long long o = __shfl_xor(best, off, 64);
      best = o < best ? o : best;
    }
    if (lane == 0) winners[t] = (unsigned)(best & 0xffffffffu);
    __syncthreads();
  }
}

// ---------------- K4: gather zq = emb[winner], idx, loss ---------------------
__global__ __launch_bounds__(256) void vq_emit(const float* __restrict__ z,
                                               const float* __restrict__ emb,
                                               const unsigned* __restrict__ winners,
                                               float* __restrict__ out_zq,
                                               float* __restrict__ out_loss,
                                               float* __restrict__ out_idx) {
  __shared__ float lsum[4];
  const int wid = threadIdx.x >> 6;
  const int lane = threadIdx.x & 63;
  const int tbase = blockIdx.x * 16 + wid * 4;
  float s_acc = 0.0f;
  #pragma unroll
  for (int it = 0; it < 4; it++) {
    int t = tbase + it;
    unsigned idx = winners[t];
    float4 e = reinterpret_cast<const float4*>(emb + (size_t)idx * DIM)[lane];
    float4 zz = reinterpret_cast<const float4*>(z + (size_t)t * DIM)[lane];
    reinterpret_cast<float4*>(out_zq + (size_t)t * DIM)[lane] = e;
    float dx = e.x - zz.x, dy = e.y - zz.y, dz = e.z - zz.z, dw = e.w - zz.w;
    s_acc += dx * dx + dy * dy + dz * dz + dw * dw;
    if (lane == 0) out_idx[t] = (float)idx;
  }
  #pragma unroll
  for (int off = 32; off > 0; off >>= 1) s_acc += __shfl_down(s_acc, off, 64);
  if (lane == 0) lsum[wid] = s_acc;
  __syncthreads();
  if (threadIdx.x == 0) {
    float tot = (lsum[0] + lsum[1] + lsum[2] + lsum[3]) * (1.25f / 8388608.0f);
    atomicAdd(out_loss, tot);
  }
}

// ====================== round-3 verified fallback path =======================
#define BT 128
#define BE 128
#define BK 32
#define LDW 132

__global__ __launch_bounds__(256) void fb_init(const float* __restrict__ z,
                                               const float* __restrict__ emb,
                                               float* __restrict__ e2,
                                               float* __restrict__ z2,
                                               unsigned long long* __restrict__ k1,
                                               float* __restrict__ loss_slot) {
  int gid = blockIdx.x * 256 + threadIdx.x;
  if (gid < NTOK) k1[gid] = ~0ull;
  if (gid == 0) loss_slot[0] = 0.0f;
  int wave = gid >> 6;
  int lane = threadIdx.x & 63;
  int row = wave * 16 + (lane >> 2);
  int sub = lane & 3;
  int q = sub & 1, h = sub >> 1;
  const float* src = (row < NTOK) ? (z + (size_t)row * DIM)
                                  : (emb + (size_t)(row - NTOK) * DIM);
  const float4* p = reinterpret_cast<const float4*>(src + h * 128 + q * 4);
  float r0, r1, r2, r3, s;
  {
    #pragma clang fp contract(off)
    r0 = 0.0f; r1 = 0.0f; r2 = 0.0f; r3 = 0.0f;
    #pragma unroll
    for (int t = 0; t < 16; t++) {
      float4 v = p[2 * t];
      float q0 = v.x * v.x, q1 = v.y * v.y, q2 = v.z * v.z, q3 = v.w * v.w;
      r0 = r0 + q0; r1 = r1 + q1; r2 = r2 + q2; r3 = r3 + q3;
    }
    s = (r0 + r1) + (r2 + r3);
    s = s + __shfl_xor(s, 1, 64);
    s = s + __shfl_xor(s, 2, 64);
  }
  if (sub == 0) {
    if (row < NTOK) z2[row] = s;
    else            e2[row - NTOK] = s;
  }
}

__global__ __launch_bounds__(256, 4) void fb_score(const float* __restrict__ z,
                                                   const float* __restrict__ emb,
                                                   const float* __restrict__ e2,
                                                   const float* __restrict__ z2,
                                                   unsigned long long* __restrict__ k1) {
  __shared__ float As[BK][LDW];
  __shared__ float Bs[BK][LDW];
  __shared__ unsigned long long mkey[BT];
  const int tid = threadIdx.x;
  const int t0 = blockIdx.x * BT;
  const int e0 = blockIdx.y * BE;
  const int tx = tid & 15;
  const int ty = tid >> 4;
  if (tid < BT) mkey[tid] = ~0ull;
  float acc[8][8];
  #pragma unroll
  for (int i = 0; i < 8; i++)
    #pragma unroll
    for (int j = 0; j < 8; j++) acc[i][j] = 0.0f;
  const float* __restrict__ zt = z + (size_t)t0 * DIM;
  const float* __restrict__ et = emb + (size_t)e0 * DIM;
  for (int kc = 0; kc < DIM; kc += BK) {
    __syncthreads();
    #pragma unroll
    for (int i = 0; i < 4; i++) {
      int f = tid + i * 256;
      int row = f >> 3;
      int kq = f & 7;
      const float4 va = *reinterpret_cast<const float4*>(zt + row * DIM + kc + kq * 4);
      const float4 vb = *reinterpret_cast<const float4*>(et + row * DIM + kc + kq * 4);
      int k = kq * 4;
      As[k + 0][row] = va.x * 2.0f; As[k + 1][row] = va.y * 2.0f;
      As[k + 2][row] = va.z * 2.0f; As[k + 3][row] = va.w * 2.0f;
      Bs[k + 0][row] = vb.x; Bs[k + 1][row] = vb.y;
      Bs[k + 2][row] = vb.z; Bs[k + 3][row] = vb.w;
    }
    __syncthreads();
    #pragma unroll 4
    for (int k = 0; k < BK; k++) {
      float a[8], b[8];
      *(float4*)&a[0] = *(const float4*)&As[k][ty * 8];
      *(float4*)&a[4] = *(const float4*)&As[k][ty * 8 + 4];
      *(float4*)&b[0] = *(const float4*)&Bs[k][tx * 8];
      *(float4*)&b[4] = *(const float4*)&Bs[k][tx * 8 + 4];
      #pragma unroll
      for (int i = 0; i < 8; i++)
        #pragma unroll
        for (int j = 0; j < 8; j++)
          acc[i][j] = fmaf(a[i], b[j], acc[i][j]);
    }
  }
  float e2c[8], z2t[8];
  *(float4*)&e2c[0] = *(const float4*)(e2 + e0 + tx * 8);
  *(float4*)&e2c[4] = *(const float4*)(e2 + e0 + tx * 8 + 4);
  *(float4*)&z2t[0] = *(const float4*)(z2 + t0 + ty * 8);
  *(float4*)&z2t[4] = *(const float4*)(z2 + t0 + ty * 8 + 4);
  {
    #pragma clang fp contract(off)
    #pragma unroll
    for (int i = 0; i < 8; i++) {
      int trow = ty * 8 + i;
      unsigned long long best = ~0ull;
      #pragma unroll
      for (int j = 0; j < 8; j++) {
        float t1 = z2t[i] - acc[i][j];
        float s = t1 + e2c[j];
        unsigned long long kk = pk64(s, e0 + tx * 8 + j);
        best = kk < best ? kk : best;
      }
      atomicMin(&mkey[trow], best);
    }
  }
  __syncthreads();
  if (tid < BT) atomicMin(&k1[t0 + tid], mkey[tid]);
}

__global__ __launch_bounds__(256) void fb_out(const float* __restrict__ z,
                                              const float* __restrict__ emb,
                                              const unsigned long long* __restrict__ k1,
                                              float* __restrict__ out_zq,
                                              float* __restrict__ out_loss,
                                              float* __restrict__ out_idx) {
  __shared__ float lsum[4];
  const int wid = threadIdx.x >> 6;
  const int lane = threadIdx.x & 63;
  const int tbase = blockIdx.x * 16 + wid * 4;
  float s_acc = 0.0f;
  #pragma unroll
  for (int it = 0; it < 4; it++) {
    int t = tbase + it;
    unsigned idx = (unsigned)(k1[t] & 0xffffffffu);
    float4 e = reinterpret_cast<const float4*>(emb + (size_t)idx * DIM)[lane];
    float4 zz = reinterpret_cast<const float4*>(z + (size_t)t * DIM)[lane];
    reinterpret_cast<float4*>(out_zq + (size_t)t * DIM)[lane] = e;
    float dx = e.x - zz.x, dy = e.y - zz.y, dz = e.z - zz.z, dw = e.w - zz.w;
    s_acc += dx * dx + dy * dy + dz * dz + dw * dw;
    if (lane == 0) out_idx[t] = (float)idx;
  }
  #pragma unroll
  for (int off = 32; off > 0; off >>= 1) s_acc += __shfl_down(s_acc, off, 64);
  if (lane == 0) lsum[wid] = s_acc;
  __syncthreads();
  if (threadIdx.x == 0) {
    float tot = (lsum[0] + lsum[1] + lsum[2] + lsum[3]) * (1.25f / 8388608.0f);
    atomicAdd(out_loss, tot);
  }
}

// ============================== launcher =====================================
extern "C" void kernel_launch(void* const* d_in, const int* in_sizes, int n_in,
                              void* d_out, int out_size, void* d_ws, size_t ws_size,
                              hipStream_t stream) {
  const float* z = (const float*)d_in[0];
  const float* emb = (const float*)d_in[1];
  float* out = (float*)d_out;
  float* out_zq = out;
  float* out_loss = out + (size_t)NTOK * DIM;
  float* out_idx = out_loss + 1;

  // ws: e2 | z2 | gmin/winners | cnt | ent(u32 x29) | work(1+NTOK) | zb | eb
  const size_t OFF_Z2   = 32768;
  const size_t OFF_GMIN = 163840;
  const size_t OFF_CNT  = 294912;
  const size_t OFF_ENT  = 425984;
  const size_t OFF_WORK = 4227072;
  const size_t OFF_ZB   = 4358400;
  const size_t OFF_EB   = 21135616;
  const size_t REQ      = 25329920;

  if (ws_size >= REQ) {
    float* e2 = (float*)d_ws;
    float* z2 = (float*)((char*)d_ws + OFF_Z2);
    unsigned* gmin = (unsigned*)((char*)d_ws + OFF_GMIN);   // reused as winners
    unsigned* cnt = (unsigned*)((char*)d_ws + OFF_CNT);
    unsigned* ent = (unsigned*)((char*)d_ws + OFF_ENT);
    unsigned* work = (unsigned*)((char*)d_ws + OFF_WORK);
    unsigned short* zb = (unsigned short*)((char*)d_ws + OFF_ZB);
    unsigned short* eb = (unsigned short*)((char*)d_ws + OFF_EB);

    hipLaunchKernelGGL(vq_prep, dim3(640), dim3(256), 0, stream,
                       z, emb, e2, z2, gmin, cnt, work, zb, eb, out_loss);
    hipLaunchKernelGGL(vq_mfma, dim3(NTOK / 128, NE / 128), dim3(256), 0, stream,
                       zb, eb, e2, gmin, cnt, ent, 0);
    hipLaunchKernelGGL(vq_mfma, dim3(NTOK / 128, NE / 128), dim3(256), 0, stream,
                       zb, eb, e2, gmin, cnt, ent, 1);
    hipLaunchKernelGGL(vq_pick, dim3(NTOK / 256), dim3(256), 0, stream,
                       cnt, ent, gmin, work);
    hipLaunchKernelGGL(vq_chain, dim3(4096), dim3(64), 0, stream,
                       z, emb, z2, e2, cnt, ent, work, gmin);
    hipLaunchKernelGGL(vq_emit, dim3(NTOK / 16), dim3(256), 0, stream,
                       z, emb, gmin, out_zq, out_loss, out_idx);
  } else {
    float* e2 = (float*)d_ws;
    float* z2 = (float*)((char*)d_ws + 32768);
    unsigned long long* k1 = (unsigned long long*)((char*)d_ws + 262144);
    hipLaunchKernelGGL(fb_init, dim3(640), dim3(256), 0, stream,
                       z, emb, e2, z2, k1, out_loss);
    hipLaunchKernelGGL(fb_score, dim3(NTOK / BT, NE / BE), dim3(256), 0, stream,
                       z, emb, e2, z2, k1);
    hipLaunchKernelGGL(fb_out, dim3(NTOK / 16), dim3(256), 0, stream,
                       z, emb, k1, out_zq, out_loss, out_idx);
  }
}